// Round 1
// baseline (14931.798 us; speedup 1.0000x reference)
//
#include <hip/hip_runtime.h>

typedef unsigned int u32;
typedef unsigned short u16;
typedef short bf16x8 __attribute__((ext_vector_type(8)));
typedef u16 u16x8 __attribute__((ext_vector_type(8)));
typedef float f32x4 __attribute__((ext_vector_type(4)));
typedef _Float16 h2v __attribute__((ext_vector_type(2)));

#define HID 256
#define NCLS 64
#define GATES 1024
#define SEQ 512
#define NBATCH 256
#define FEAT 512
#define INDIM 576

// ---------- helpers ----------
__device__ __forceinline__ u16 f2b(float f) {              // fp32 -> bf16 RNE
  u32 u = __builtin_bit_cast(u32, f);
  u += 0x7fffu + ((u >> 16) & 1u);
  return (u16)(u >> 16);
}
__device__ __forceinline__ float b2f(u16 v) {
  u32 u = ((u32)v) << 16;
  return __builtin_bit_cast(float, u);
}
__device__ __forceinline__ u32 packh2(float a, float b) {  // two fp32 -> packed f16x2
  u16 lo = __builtin_bit_cast(u16, (_Float16)a);
  u16 hi = __builtin_bit_cast(u16, (_Float16)b);
  return (u32)lo | ((u32)hi << 16);
}
__device__ __forceinline__ float fdot2a(u32 h, u32 w, float c) {
#if __has_builtin(__builtin_amdgcn_fdot2)
  return __builtin_amdgcn_fdot2(__builtin_bit_cast(h2v, h),
                                __builtin_bit_cast(h2v, w), c, false);
#else
  h2v a = __builtin_bit_cast(h2v, h);
  h2v b = __builtin_bit_cast(h2v, w);
  return c + (float)a[0] * (float)b[0] + (float)a[1] * (float)b[1];
#endif
}
__device__ __forceinline__ float sigmf_(float x) { return 1.f / (1.f + __expf(-x)); }
__device__ __forceinline__ float tanhf_(float x) { return 1.f - 2.f / (1.f + __expf(2.f * x)); }

// ---------- kernel 0: weight prep + out zero ----------
// Wihk  : bf16 [1024][512]   (x-part of W_ih)
// Whh_pk: f16x2 [128][1024]  Whh_pk[k2][g] = (W_hh[g][2k2], W_hh[g][2k2+1])
// Woh_t : f32 [64][1024]     Woh_t[p][g] = W_ih[g][512+p]
// Wout_pk: f16x2 [128][64]   Wout_pk[k2][c] = (W_out[c][2k2], W_out[c][2k2+1])
__global__ void prep_kernel(const float* __restrict__ W_ih, const float* __restrict__ W_hh,
                            const float* __restrict__ W_out,
                            u16* __restrict__ Wihk, u32* __restrict__ Whh_pk,
                            float* __restrict__ Woh_t, u32* __restrict__ Wout_pk,
                            float* __restrict__ out) {
  int idx = blockIdx.x * 256 + threadIdx.x;
  const int N0 = 1024 * 512;          // Wihk
  const int N1 = N0 + 128 * 1024;     // Whh_pk
  const int N2 = N1 + 64 * 1024;      // Woh_t
  const int N3 = N2 + 128 * 64;       // Wout_pk
  if (idx < N0) {
    int g = idx >> 9, k = idx & 511;
    Wihk[idx] = f2b(W_ih[g * INDIM + k]);
  } else if (idx < N1) {
    int i = idx - N0;
    int k2 = i >> 10, g = i & 1023;
    Whh_pk[i] = packh2(W_hh[g * HID + 2 * k2], W_hh[g * HID + 2 * k2 + 1]);
  } else if (idx < N2) {
    int i = idx - N1;
    int p = i >> 10, g = i & 1023;
    Woh_t[i] = W_ih[g * INDIM + FEAT + p];
  } else if (idx < N3) {
    int i = idx - N2;
    int k2 = i >> 6, c = i & 63;
    Wout_pk[i] = packh2(W_out[c * HID + 2 * k2], W_out[c * HID + 2 * k2 + 1]);
  } else if (idx == N3) {
    out[0] = 0.f;
  }
}

// ---------- kernel 1: Xp = bf16( x @ W_ih[:, :512]^T + b_ih + b_hh ) ----------
// 128x128 tile, BK=32, 4 waves in 2x2, each wave 4x4 tiles of 16x16x32 bf16 MFMA.
__global__ __launch_bounds__(256) void gemm_xp(const float* __restrict__ x,
                                               const u16* __restrict__ Wihk,
                                               const float* __restrict__ b_ih,
                                               const float* __restrict__ b_hh,
                                               u16* __restrict__ Xp) {
  __shared__ u16 As[128 * 32];
  __shared__ u16 Bs[128 * 32];
  const int tid = threadIdx.x;
  const int bx = blockIdx.x;
  const int m0 = (bx >> 3) * 128;
  const int n0 = (bx & 7) * 128;
  const int wave = tid >> 6, lane = tid & 63;
  const int wm = (wave >> 1) * 64, wn = (wave & 1) * 64;
  const int l16 = lane & 15, quad = lane >> 4;
  const int r = tid >> 2;             // 0..63
  const int c8 = (tid & 3) * 8;       // 0,8,16,24

  f32x4 zero4 = {0.f, 0.f, 0.f, 0.f};
  f32x4 acc[4][4];
#pragma unroll
  for (int i = 0; i < 4; ++i)
#pragma unroll
    for (int j = 0; j < 4; ++j) acc[i][j] = zero4;

  for (int k0 = 0; k0 < FEAT; k0 += 32) {
    // stage A: x fp32 -> bf16
#pragma unroll
    for (int p = 0; p < 2; ++p) {
      const float* src = x + (size_t)(m0 + r + p * 64) * FEAT + k0 + c8;
      float4 f0 = *(const float4*)src;
      float4 f1 = *(const float4*)(src + 4);
      u16x8 v;
      v[0] = f2b(f0.x); v[1] = f2b(f0.y); v[2] = f2b(f0.z); v[3] = f2b(f0.w);
      v[4] = f2b(f1.x); v[5] = f2b(f1.y); v[6] = f2b(f1.z); v[7] = f2b(f1.w);
      *(u16x8*)&As[(r + p * 64) * 32 + c8] = v;
    }
    // stage B: bf16 copy
#pragma unroll
    for (int p = 0; p < 2; ++p) {
      *(uint4*)&Bs[(r + p * 64) * 32 + c8] =
          *(const uint4*)&Wihk[(size_t)(n0 + r + p * 64) * FEAT + k0 + c8];
    }
    __syncthreads();
    bf16x8 am[4], bn[4];
#pragma unroll
    for (int i = 0; i < 4; ++i)
      am[i] = *(const bf16x8*)&As[(wm + i * 16 + l16) * 32 + quad * 8];
#pragma unroll
    for (int j = 0; j < 4; ++j)
      bn[j] = *(const bf16x8*)&Bs[(wn + j * 16 + l16) * 32 + quad * 8];
#pragma unroll
    for (int i = 0; i < 4; ++i)
#pragma unroll
      for (int j = 0; j < 4; ++j)
        acc[i][j] = __builtin_amdgcn_mfma_f32_16x16x32_bf16(am[i], bn[j], acc[i][j], 0, 0, 0);
    __syncthreads();
  }

  // epilogue: add bias, round to bf16
  float bias[4];
  int cols[4];
#pragma unroll
  for (int j = 0; j < 4; ++j) {
    cols[j] = n0 + wn + j * 16 + l16;
    bias[j] = b_ih[cols[j]] + b_hh[cols[j]];
  }
#pragma unroll
  for (int i = 0; i < 4; ++i) {
    int rowb = m0 + wm + i * 16 + quad * 4;
#pragma unroll
    for (int j = 0; j < 4; ++j) {
#pragma unroll
      for (int rr = 0; rr < 4; ++rr) {
        Xp[(size_t)(rowb + rr) * GATES + cols[j]] = f2b(acc[i][j][rr] + bias[j]);
      }
    }
  }
}

// ---------- kernel 2: persistent recurrent decoder ----------
// 128 blocks x 2 batch, 512 threads (8 waves). Per step:
//  (a) gates = Xp + Woh_t[pred] + h @ W_hh^T  (f16 dot2, W from L2)
//  (b) LSTM activations (c in regs), h -> f16 LDS
//  (c) warps 0/1: logits via dot2, wave64 shuffle argmax + log-softmax, NLL accum
__global__ __launch_bounds__(512) void lstm_seq(const u16* __restrict__ Xp,
                                                const u32* __restrict__ Whh_pk,
                                                const float* __restrict__ Woh_t,
                                                const u32* __restrict__ Wout_pk,
                                                const float* __restrict__ b_out,
                                                const int* __restrict__ tag,
                                                float* __restrict__ out) {
  __shared__ float gbuf[2][GATES];                 // 8 KB
  __shared__ __align__(16) u32 h2lds[2 * 128];     // h as f16 pairs, 1 KB
  __shared__ int predl[2];

  const int tid = threadIdx.x;
  const int b0 = blockIdx.x * 2;
  const int warp = tid >> 6, lane = tid & 63;
  const int g2 = tid * 2;                // gate pair owned in matvec
  const int bact = tid >> 8, jact = tid & 255;  // activation mapping

  if (tid < 256) h2lds[tid] = 0u;
  if (tid < 2) predl[tid] = 0;
  float c_reg = 0.f;
  float loss_acc = 0.f;
  __syncthreads();

#pragma unroll 1
  for (int s = 0; s < SEQ; ++s) {
    // ---- (a) matvec: gates for both batch rows ----
    int p0 = predl[0], p1 = predl[1];
    u32 u0 = *(const u32*)(Xp + ((size_t)(b0 + 0) * SEQ + s) * GATES + g2);
    u32 u1 = *(const u32*)(Xp + ((size_t)(b0 + 1) * SEQ + s) * GATES + g2);
    float2 oh0 = *(const float2*)(Woh_t + p0 * GATES + g2);
    float2 oh1 = *(const float2*)(Woh_t + p1 * GATES + g2);
    float a00 = b2f((u16)(u0 & 0xffff)) + oh0.x;
    float a01 = b2f((u16)(u0 >> 16)) + oh0.y;
    float a10 = b2f((u16)(u1 & 0xffff)) + oh1.x;
    float a11 = b2f((u16)(u1 >> 16)) + oh1.y;

    for (int kc = 0; kc < 32; ++kc) {
      uint4 h0v = *(const uint4*)&h2lds[kc * 4];
      uint4 h1v = *(const uint4*)&h2lds[128 + kc * 4];
      u32 h0a[4] = {h0v.x, h0v.y, h0v.z, h0v.w};
      u32 h1a[4] = {h1v.x, h1v.y, h1v.z, h1v.w};
#pragma unroll
      for (int t = 0; t < 4; ++t) {
        uint2 w = *(const uint2*)&Whh_pk[(size_t)(kc * 4 + t) * GATES + g2];
        a00 = fdot2a(h0a[t], w.x, a00);
        a01 = fdot2a(h0a[t], w.y, a01);
        a10 = fdot2a(h1a[t], w.x, a10);
        a11 = fdot2a(h1a[t], w.y, a11);
      }
    }
    gbuf[0][g2] = a00; gbuf[0][g2 + 1] = a01;
    gbuf[1][g2] = a10; gbuf[1][g2 + 1] = a11;
    __syncthreads();

    // ---- (b) LSTM cell (torch gate order i,f,g,o) ----
    {
      float ig = gbuf[bact][jact];
      float fg = gbuf[bact][jact + 256];
      float gg = gbuf[bact][jact + 512];
      float og = gbuf[bact][jact + 768];
      float iv = sigmf_(ig), fv = sigmf_(fg), gv = tanhf_(gg), ov = sigmf_(og);
      c_reg = fv * c_reg + iv * gv;
      float h = ov * tanhf_(c_reg);
      ((u16*)h2lds)[bact * 256 + jact] = __builtin_bit_cast(u16, (_Float16)h);
    }
    __syncthreads();

    // ---- (c) logits + argmax + log-softmax (warp w handles batch row w) ----
    if (warp < 2) {
      int b = warp;
      int cls = lane;
      float lg = b_out[cls];
      for (int kc = 0; kc < 32; ++kc) {
        uint4 hv = *(const uint4*)&h2lds[b * 128 + kc * 4];
        u32 ha[4] = {hv.x, hv.y, hv.z, hv.w};
#pragma unroll
        for (int t = 0; t < 4; ++t)
          lg = fdot2a(ha[t], Wout_pk[(kc * 4 + t) * NCLS + cls], lg);
      }
      // wave-wide max+argmax (first index wins ties)
      float v = lg; int ii = cls;
#pragma unroll
      for (int off = 32; off; off >>= 1) {
        float ov = __shfl_xor(v, off);
        int oi = __shfl_xor(ii, off);
        if (ov > v || (ov == v && oi < ii)) { v = ov; ii = oi; }
      }
      float e = __expf(lg - v);
      float ssum = e;
#pragma unroll
      for (int off = 32; off; off >>= 1) ssum += __shfl_xor(ssum, off);
      int t = tag[(size_t)(b0 + b) * SEQ + s];
      float lt = __shfl(lg, t < 0 ? 0 : t);
      if (t >= 0) loss_acc += v + __logf(ssum) - lt;
      if (lane == 0) predl[b] = ii;
    }
    __syncthreads();
  }
  if (warp < 2 && lane == 0) atomicAdd(out, loss_acc);
}

// ---------- launcher ----------
extern "C" void kernel_launch(void* const* d_in, const int* in_sizes, int n_in,
                              void* d_out, int out_size, void* d_ws, size_t ws_size,
                              hipStream_t stream) {
  const float* x     = (const float*)d_in[0];
  const int*   tag   = (const int*)d_in[1];
  const float* W_ih  = (const float*)d_in[2];
  const float* W_hh  = (const float*)d_in[3];
  const float* b_ih  = (const float*)d_in[4];
  const float* b_hh  = (const float*)d_in[5];
  const float* W_out = (const float*)d_in[6];
  const float* b_out = (const float*)d_in[7];
  float* out = (float*)d_out;

  char* w = (char*)d_ws;
  // ws layout (bytes):
  //   Xp (bf16)  : 131072*1024*2 = 268,435,456
  //   Wihk (bf16): 1024*512*2    =   1,048,576
  //   Whh_pk     : 128*1024*4    =     524,288
  //   Woh_t      : 64*1024*4     =     262,144
  //   Wout_pk    : 128*64*4      =      32,768
  u16* Xp      = (u16*)w;
  u16* Wihk    = (u16*)(w + 268435456ull);
  u32* Whh_pk  = (u32*)(w + 269484032ull);
  float* Woh_t = (float*)(w + 270008320ull);
  u32* Wout_pk = (u32*)(w + 270270464ull);

  prep_kernel<<<2849, 256, 0, stream>>>(W_ih, W_hh, W_out, Wihk, Whh_pk, Woh_t, Wout_pk, out);
  gemm_xp<<<8192, 256, 0, stream>>>(x, Wihk, b_ih, b_hh, Xp);
  lstm_seq<<<128, 512, 0, stream>>>(Xp, Whh_pk, Woh_t, Wout_pk, b_out, tag, out);
}

// Round 2
// 3063.395 us; speedup vs baseline: 4.8743x; 4.8743x over previous
//
#include <hip/hip_runtime.h>

typedef unsigned int u32;
typedef unsigned short u16;
typedef short bf16x8 __attribute__((ext_vector_type(8)));
typedef u16 u16x8 __attribute__((ext_vector_type(8)));
typedef float f32x4 __attribute__((ext_vector_type(4)));
typedef _Float16 h2v __attribute__((ext_vector_type(2)));

#define HID 256
#define NCLS 64
#define GATES 1024
#define SEQ 512
#define NBATCH 256
#define FEAT 512
#define INDIM 576

// ---------- helpers ----------
__device__ __forceinline__ u16 f2b(float f) {              // fp32 -> bf16 RNE
  u32 u = __builtin_bit_cast(u32, f);
  u += 0x7fffu + ((u >> 16) & 1u);
  return (u16)(u >> 16);
}
__device__ __forceinline__ float b2f(u16 v) {
  u32 u = ((u32)v) << 16;
  return __builtin_bit_cast(float, u);
}
__device__ __forceinline__ u32 packh2(float a, float b) {  // two fp32 -> packed f16x2
  u16 lo = __builtin_bit_cast(u16, (_Float16)a);
  u16 hi = __builtin_bit_cast(u16, (_Float16)b);
  return (u32)lo | ((u32)hi << 16);
}
__device__ __forceinline__ float fdot2a(u32 h, u32 w, float c) {
#if __has_builtin(__builtin_amdgcn_fdot2)
  return __builtin_amdgcn_fdot2(__builtin_bit_cast(h2v, h),
                                __builtin_bit_cast(h2v, w), c, false);
#else
  h2v a = __builtin_bit_cast(h2v, h);
  h2v b = __builtin_bit_cast(h2v, w);
  return c + (float)a[0] * (float)b[0] + (float)a[1] * (float)b[1];
#endif
}
__device__ __forceinline__ float sigmf_(float x) { return 1.f / (1.f + __expf(-x)); }
__device__ __forceinline__ float tanhf_(float x) { return 1.f - 2.f / (1.f + __expf(2.f * x)); }

// ---------- kernel 0: weight prep + out zero ----------
// Wihk  : bf16 [1024][512]        x-part of W_ih (for GEMM)
// WhhR  : u32  [192][512]         register-resident W_hh part, K in [0,192)
//         i<96: gate g=t, kpair=i ; i>=96: gate g=t+512, kpair=i-96
// WhhL  : u32  [8][1024][4]       LDS-resident W_hh part, K in [192,256)
// WoutR : u32  [16][512]          W_out f16 pairs; t -> (c=t&63, kq=t>>6), K=kq*32+2j
// Woh_t : f32  [64][1024]         Woh_t[p][g] = W_ih[g][512+p]
__global__ void prep_kernel(const float* __restrict__ W_ih, const float* __restrict__ W_hh,
                            const float* __restrict__ W_out,
                            u16* __restrict__ Wihk, u32* __restrict__ WhhR,
                            u32* __restrict__ WhhL, u32* __restrict__ WoutR,
                            float* __restrict__ Woh_t, float* __restrict__ out) {
  int idx = blockIdx.x * 256 + threadIdx.x;
  const int N0 = 1024 * 512;            // Wihk
  const int N1 = N0 + 192 * 512;        // WhhR
  const int N2 = N1 + 8 * 1024 * 4;     // WhhL
  const int N3 = N2 + 16 * 512;         // WoutR
  const int N4 = N3 + 64 * 1024;        // Woh_t
  if (idx < N0) {
    int g = idx >> 9, k = idx & 511;
    Wihk[idx] = f2b(W_ih[g * INDIM + k]);
  } else if (idx < N1) {
    int r = idx - N0;
    int i = r >> 9, t = r & 511;
    int g = (i < 96) ? t : t + 512;
    int kp = (i < 96) ? i : i - 96;
    WhhR[r] = packh2(W_hh[g * HID + 2 * kp], W_hh[g * HID + 2 * kp + 1]);
  } else if (idx < N2) {
    int r = idx - N1;
    int q = r & 3, g = (r >> 2) & 1023, c = r >> 12;
    int kp = 96 + c * 4 + q;
    WhhL[r] = packh2(W_hh[g * HID + 2 * kp], W_hh[g * HID + 2 * kp + 1]);
  } else if (idx < N3) {
    int r = idx - N2;
    int j = r >> 9, t = r & 511;
    int cc = t & 63, kq = t >> 6;
    int k0 = kq * 32 + 2 * j;
    WoutR[r] = packh2(W_out[cc * HID + k0], W_out[cc * HID + k0 + 1]);
  } else if (idx < N4) {
    int r = idx - N3;
    int p = r >> 10, g = r & 1023;
    Woh_t[r] = W_ih[g * INDIM + FEAT + p];
  } else if (idx == N4) {
    out[0] = 0.f;
  }
}

// ---------- kernel 1: Xp = bf16( x @ W_ih[:, :512]^T + b_ih + b_hh ) ----------
__global__ __launch_bounds__(256) void gemm_xp(const float* __restrict__ x,
                                               const u16* __restrict__ Wihk,
                                               const float* __restrict__ b_ih,
                                               const float* __restrict__ b_hh,
                                               u16* __restrict__ Xp) {
  __shared__ u16 As[128 * 32];
  __shared__ u16 Bs[128 * 32];
  const int tid = threadIdx.x;
  const int bx = blockIdx.x;
  const int m0 = (bx >> 3) * 128;
  const int n0 = (bx & 7) * 128;
  const int wave = tid >> 6, lane = tid & 63;
  const int wm = (wave >> 1) * 64, wn = (wave & 1) * 64;
  const int l16 = lane & 15, quad = lane >> 4;
  const int r = tid >> 2;
  const int c8 = (tid & 3) * 8;

  f32x4 zero4 = {0.f, 0.f, 0.f, 0.f};
  f32x4 acc[4][4];
#pragma unroll
  for (int i = 0; i < 4; ++i)
#pragma unroll
    for (int j = 0; j < 4; ++j) acc[i][j] = zero4;

  for (int k0 = 0; k0 < FEAT; k0 += 32) {
#pragma unroll
    for (int p = 0; p < 2; ++p) {
      const float* src = x + (size_t)(m0 + r + p * 64) * FEAT + k0 + c8;
      float4 f0 = *(const float4*)src;
      float4 f1 = *(const float4*)(src + 4);
      u16x8 v;
      v[0] = f2b(f0.x); v[1] = f2b(f0.y); v[2] = f2b(f0.z); v[3] = f2b(f0.w);
      v[4] = f2b(f1.x); v[5] = f2b(f1.y); v[6] = f2b(f1.z); v[7] = f2b(f1.w);
      *(u16x8*)&As[(r + p * 64) * 32 + c8] = v;
    }
#pragma unroll
    for (int p = 0; p < 2; ++p) {
      *(uint4*)&Bs[(r + p * 64) * 32 + c8] =
          *(const uint4*)&Wihk[(size_t)(n0 + r + p * 64) * FEAT + k0 + c8];
    }
    __syncthreads();
    bf16x8 am[4], bn[4];
#pragma unroll
    for (int i = 0; i < 4; ++i)
      am[i] = *(const bf16x8*)&As[(wm + i * 16 + l16) * 32 + quad * 8];
#pragma unroll
    for (int j = 0; j < 4; ++j)
      bn[j] = *(const bf16x8*)&Bs[(wn + j * 16 + l16) * 32 + quad * 8];
#pragma unroll
    for (int i = 0; i < 4; ++i)
#pragma unroll
      for (int j = 0; j < 4; ++j)
        acc[i][j] = __builtin_amdgcn_mfma_f32_16x16x32_bf16(am[i], bn[j], acc[i][j], 0, 0, 0);
    __syncthreads();
  }

  float bias[4];
  int cols[4];
#pragma unroll
  for (int j = 0; j < 4; ++j) {
    cols[j] = n0 + wn + j * 16 + l16;
    bias[j] = b_ih[cols[j]] + b_hh[cols[j]];
  }
#pragma unroll
  for (int i = 0; i < 4; ++i) {
    int rowb = m0 + wm + i * 16 + quad * 4;
#pragma unroll
    for (int j = 0; j < 4; ++j) {
#pragma unroll
      for (int rr = 0; rr < 4; ++rr) {
        Xp[(size_t)(rowb + rr) * GATES + cols[j]] = f2b(acc[i][j][rr] + bias[j]);
      }
    }
  }
}

// ---------- kernel 2: persistent recurrent decoder, W_hh CU-resident ----------
// 256 blocks (1 batch row each) x 512 threads. Thread t owns gates t and t+512.
// W_hh K[0,192): 192 VGPRs/thread. K[192,256): 128 KB LDS. W_out: 16 VGPRs.
__global__ __launch_bounds__(512, 2) void lstm_seq(
    const u16* __restrict__ Xp, const u32* __restrict__ WhhR,
    const uint4* __restrict__ WhhL, const u32* __restrict__ WoutR,
    const float* __restrict__ Woh, const float* __restrict__ b_out,
    const int* __restrict__ tag, float* __restrict__ out) {
  extern __shared__ u32 smem[];
  uint4* whhl = (uint4*)smem;            // [0, 32768) u32 : 8*1024 uint4
  float* gbuf = (float*)(smem + 32768);  // 1024 f32
  u32* h_u32 = smem + 33792;             // 128 u32 (256 f16)
  float* pbuf = (float*)(smem + 33920);  // 512 f32
  int* tag_l = (int*)(smem + 34432);     // 512 i32
  int* predv = (int*)(smem + 34944);

  const int tid = threadIdx.x;
  const int b = blockIdx.x;

  // ---- init: weights into registers / LDS ----
  u32 wr[192];
#pragma unroll
  for (int i = 0; i < 192; ++i) wr[i] = WhhR[i * 512 + tid];
  u32 wo[16];
#pragma unroll
  for (int i = 0; i < 16; ++i) wo[i] = WoutR[i * 512 + tid];
#pragma unroll
  for (int i = 0; i < 16; ++i) whhl[i * 512 + tid] = WhhL[i * 512 + tid];
  tag_l[tid] = tag[b * SEQ + tid];
  if (tid < 128) h_u32[tid] = 0u;
  if (tid == 0) predv[0] = 0;
  float c_reg = 0.f;
  float bout_c = (tid < 64) ? b_out[tid] : 0.f;
  float loss_acc = 0.f;
  const u16* xp_row = Xp + (size_t)b * SEQ * GATES;
  u16 xpa = xp_row[tid];
  u16 xpb = xp_row[tid + 512];
  __syncthreads();

#pragma unroll 1
  for (int s = 0; s < SEQ; ++s) {
    // ---- phase A: gates matvec ----
    int pred = predv[0];
    float oha = Woh[pred * GATES + tid];          // issued early, used at end
    float ohb = Woh[pred * GATES + tid + 512];
    int sn = (s + 1 < SEQ) ? s + 1 : s;
    u16 xpa_n = xp_row[sn * GATES + tid];         // prefetch next step
    u16 xpb_n = xp_row[sn * GATES + tid + 512];

    float acc0 = b2f(xpa);
    float acc1 = b2f(xpb);
#pragma unroll
    for (int c = 0; c < 24; ++c) {                // K [0,192) from registers
      uint4 h4 = *(const uint4*)(h_u32 + c * 4);
      u32 ha[4] = {h4.x, h4.y, h4.z, h4.w};
#pragma unroll
      for (int q = 0; q < 4; ++q) {
        acc0 = fdot2a(ha[q], wr[c * 4 + q], acc0);
        acc1 = fdot2a(ha[q], wr[96 + c * 4 + q], acc1);
      }
    }
#pragma unroll
    for (int c = 0; c < 8; ++c) {                 // K [192,256) from LDS
      uint4 h4 = *(const uint4*)(h_u32 + 96 + c * 4);
      uint4 w0 = whhl[c * 1024 + tid];
      uint4 w1 = whhl[c * 1024 + tid + 512];
      u32 ha[4] = {h4.x, h4.y, h4.z, h4.w};
      u32 w0a[4] = {w0.x, w0.y, w0.z, w0.w};
      u32 w1a[4] = {w1.x, w1.y, w1.z, w1.w};
#pragma unroll
      for (int q = 0; q < 4; ++q) {
        acc0 = fdot2a(ha[q], w0a[q], acc0);
        acc1 = fdot2a(ha[q], w1a[q], acc1);
      }
    }
    gbuf[tid] = acc0 + oha;
    gbuf[tid + 512] = acc1 + ohb;
    __syncthreads();

    // ---- phase B: LSTM cell (i,f,g,o), c in regs of threads 0..255 ----
    if (tid < 256) {
      float ig = gbuf[tid];
      float fg = gbuf[tid + 256];
      float gg = gbuf[tid + 512];
      float og = gbuf[tid + 768];
      float iv = sigmf_(ig), fv = sigmf_(fg), gv = tanhf_(gg), ov = sigmf_(og);
      c_reg = fv * c_reg + iv * gv;
      float h = ov * tanhf_(c_reg);
      ((u16*)h_u32)[tid] = __builtin_bit_cast(u16, (_Float16)h);
    }
    __syncthreads();

    // ---- phase C1: partial logits, thread -> (class = tid&63, kq = tid>>6) ----
    {
      int kq = tid >> 6;
      float p = 0.f;
#pragma unroll
      for (int c = 0; c < 4; ++c) {
        uint4 h4 = *(const uint4*)(h_u32 + kq * 16 + c * 4);
        u32 ha[4] = {h4.x, h4.y, h4.z, h4.w};
#pragma unroll
        for (int q = 0; q < 4; ++q) p = fdot2a(ha[q], wo[c * 4 + q], p);
      }
      pbuf[tid] = p;
    }
    __syncthreads();

    // ---- phase C2: wave 0 reduces, argmax + log-softmax + NLL ----
    if (tid < 64) {
      float lg = bout_c;
#pragma unroll
      for (int k = 0; k < 8; ++k) lg += pbuf[k * 64 + tid];
      float v = lg; int ii = tid;
#pragma unroll
      for (int off = 32; off; off >>= 1) {
        float ov = __shfl_xor(v, off);
        int oi = __shfl_xor(ii, off);
        if (ov > v || (ov == v && oi < ii)) { v = ov; ii = oi; }
      }
      float ssum = __expf(lg - v);
#pragma unroll
      for (int off = 32; off; off >>= 1) ssum += __shfl_xor(ssum, off);
      int t = tag_l[s];
      float lt = __shfl(lg, t & 63);
      if (t >= 0) loss_acc += v + __logf(ssum) - lt;
      if (tid == 0) predv[0] = ii;
    }
    xpa = xpa_n; xpb = xpb_n;
    __syncthreads();
  }
  if (tid == 0) atomicAdd(out, loss_acc);
}

// ---------- launcher ----------
extern "C" void kernel_launch(void* const* d_in, const int* in_sizes, int n_in,
                              void* d_out, int out_size, void* d_ws, size_t ws_size,
                              hipStream_t stream) {
  const float* x     = (const float*)d_in[0];
  const int*   tag   = (const int*)d_in[1];
  const float* W_ih  = (const float*)d_in[2];
  const float* W_hh  = (const float*)d_in[3];
  const float* b_ih  = (const float*)d_in[4];
  const float* b_hh  = (const float*)d_in[5];
  const float* W_out = (const float*)d_in[6];
  const float* b_out = (const float*)d_in[7];
  float* out = (float*)d_out;

  char* w = (char*)d_ws;
  // ws layout (bytes):
  //   Xp    @ 0          : 268,435,456
  //   Wihk  @ 268435456  :   1,048,576
  //   WhhR  @ 269484032  :     393,216
  //   WhhL  @ 269877248  :     131,072
  //   WoutR @ 270008320  :      32,768
  //   Woh   @ 270041088  :     262,144
  u16* Xp      = (u16*)w;
  u16* Wihk    = (u16*)(w + 268435456ull);
  u32* WhhR    = (u32*)(w + 269484032ull);
  u32* WhhL    = (u32*)(w + 269877248ull);
  u32* WoutR   = (u32*)(w + 270008320ull);
  float* Woh   = (float*)(w + 270041088ull);

  const int smem_bytes = 34945 * 4;  // 139,780 B dynamic LDS (<=160 KB/CU)
  (void)hipFuncSetAttribute((const void*)lstm_seq,
                            hipFuncAttributeMaxDynamicSharedMemorySize, smem_bytes);

  prep_kernel<<<2849, 256, 0, stream>>>(W_ih, W_hh, W_out, Wihk, WhhR, WhhL, WoutR, Woh, out);
  gemm_xp<<<8192, 256, 0, stream>>>(x, Wihk, b_ih, b_hh, Xp);
  lstm_seq<<<256, 512, smem_bytes, stream>>>(Xp, WhhR, (const uint4*)WhhL, WoutR, Woh, b_out, tag, out);
}